// Round 5
// baseline (1017.782 us; speedup 1.0000x reference)
//
#include <hip/hip_runtime.h>
#include <stdint.h>

#define E_ 8
#define D_ 1024
#define F_ 4096
#define NTOK 8192
#define NASSIGN 16384
#define CAP 18432   // 16384 + 8*256 worst-case padding, multiple of 256

typedef __attribute__((ext_vector_type(8))) short short8;
typedef __attribute__((ext_vector_type(8))) __bf16 bf16x8;
typedef __attribute__((ext_vector_type(4))) float f32x4;

__device__ __forceinline__ ushort f2bf(float f) {
  uint32_t u = __float_as_uint(f);
  uint32_t r = (u + 0x7fffu + ((u >> 16) & 1u)) >> 16;
  return (ushort)r;
}

__device__ __forceinline__ f32x4 mfma16(short8 a, short8 b, f32x4 c) {
  return __builtin_amdgcn_mfma_f32_16x16x32_bf16(
      __builtin_bit_cast(bf16x8, a), __builtin_bit_cast(bf16x8, b), c, 0, 0, 0);
}

// async global->LDS, 16B per lane. LDS dest is wave-uniform base + lane*16.
__device__ __forceinline__ void gld16(const ushort* g, ushort* l) {
  __builtin_amdgcn_global_load_lds(
      (const __attribute__((address_space(1))) unsigned int*)(const void*)g,
      (__attribute__((address_space(3))) unsigned int*)(void*)l, 16, 0, 0);
}

// ================= 8-phase 256x256 BK=64 K-loop machinery =================
// LDS: 128 KiB = buf0{A 32K | B 32K} buf1{A 32K | B 32K} (ushort units below).
// Tile layout per buffer: 256 rows x 8 chunks of 16B; physical slot s of row r
// holds logical k-chunk (s ^ (r&7))  [proven zero-conflict].
// Staging: linear LDS dest + pre-swizzled global source (both-sides rule).
// Regions (8KB = 1 gld16 x 512 thr): A-pair r = rows {r*32..+31} of both
// halves; B r = rows {r*64..+63}.
//
// vmcnt is PER-WAVE: every counted wait sits BEFORE an s_barrier so all
// waves' staging is complete before any wave reads:
//   prologue: 14 issued; VMW(6)+bar completes buf0 tile0 (first 8).
//   ph3-end VMW(6): completes through ph0's stage -> buf1 tile ready for ph4.
//   ph7-end VMW(6): completes through ph4's stage -> buf0 tile ready for ph0'.
//   final iter: ph3-end VMW(0); no stages after.
// sched_barrier(0) placement (round-5 diet): after lgkmcnt(0) (rule-18 fence)
// and bracketing the end s_barrier (blocks next-phase read hoisting above the
// barrier -- the ph3/ph7 cross-wave staging race).

#define VMW(N) do { asm volatile("s_waitcnt vmcnt(" #N ")" ::: "memory"); \
  __builtin_amdgcn_sched_barrier(0); } while (0)

#define RD_A(BUF, I, KK) \
  (*(const short8*)&lds[(BUF)*32768 + \
     ((wm*128 + (I)*16 + l15) * 8 + \
      (((KK)*4 + quad) ^ ((wm*128 + (I)*16 + l15) & 7))) * 8])

#define RD_B(BUF, J, KK) \
  (*(const short8*)&lds[(BUF)*32768 + 16384 + \
     ((wn*64 + (J)*16 + l15) * 8 + \
      (((KK)*4 + quad) ^ ((wn*64 + (J)*16 + l15) & 7))) * 8])

#define STG_A(BUF, R, KO) \
  gld16(ap[(R)] + (KO), &lds[(BUF)*32768 + ahalf + (R)*2048 + alane])
#define STG_B(BUF, R, KO, KD) \
  gld16(bpb + (size_t)(R)*64*(KD) + (KO), \
        &lds[(BUF)*32768 + 16384 + (R)*4096 + blane])

// one phase: {12 or 4 ds_read_b128 || stage 2 regions} -> bar -> lgkm(0) ->
// setprio(1) 16 MFMA setprio(0) -> [counted vmcnt] -> bar.
#define PHASE(BUF, Q, STG, ENDW) do { \
  short8 aA0, aA1, aB0, aB1; \
  if ((Q) == 0) { \
    _Pragma("unroll") \
    for (int j = 0; j < 4; j++) { \
      b[j][0] = RD_B(BUF, j, 0); b[j][1] = RD_B(BUF, j, 1); \
    } \
  } \
  aA0 = RD_A(BUF, 2*(Q), 0);   aA1 = RD_A(BUF, 2*(Q), 1); \
  aB0 = RD_A(BUF, 2*(Q)+1, 0); aB1 = RD_A(BUF, 2*(Q)+1, 1); \
  STG; \
  __builtin_amdgcn_s_barrier(); \
  asm volatile("s_waitcnt lgkmcnt(0)" ::: "memory"); \
  __builtin_amdgcn_sched_barrier(0); \
  __builtin_amdgcn_s_setprio(1); \
  _Pragma("unroll") \
  for (int j = 0; j < 4; j++) { \
    acc[2*(Q)][j]   = mfma16(aA0, b[j][0], acc[2*(Q)][j]); \
    acc[2*(Q)][j]   = mfma16(aA1, b[j][1], acc[2*(Q)][j]); \
    acc[2*(Q)+1][j] = mfma16(aB0, b[j][0], acc[2*(Q)+1][j]); \
    acc[2*(Q)+1][j] = mfma16(aB1, b[j][1], acc[2*(Q)+1][j]); \
  } \
  __builtin_amdgcn_s_setprio(0); \
  ENDW; \
  __builtin_amdgcn_sched_barrier(0); \
  __builtin_amdgcn_s_barrier(); \
  __builtin_amdgcn_sched_barrier(0); \
} while (0)

// prologue: tile0 all 8 regions + tile1 first 6 (14 in flight), then
// VMW(6)+barrier so every wave's buf0-tile0 portion is visible before reads.
#define PROLOGUE(KD) do { \
  STG_B(0,0,0,KD); STG_B(0,1,0,KD); STG_B(0,2,0,KD); STG_B(0,3,0,KD); \
  STG_A(0,0,0); STG_A(0,1,0); STG_A(0,2,0); STG_A(0,3,0); \
  STG_B(1,0,64,KD); STG_B(1,1,64,KD); STG_B(1,2,64,KD); STG_B(1,3,64,KD); \
  STG_A(1,0,64); STG_A(1,1,64); \
  VMW(6); \
  __builtin_amdgcn_s_barrier(); \
  __builtin_amdgcn_sched_barrier(0); \
} while (0)

#define EIGHT_PHASE_LOOP(TT, KD) do { \
  _Pragma("unroll 1") \
  for (int t = 0; t < (TT) - 1; ++t) { \
    int ko1 = (2*t+1)*64, ko2 = (2*t+2)*64, ko3 = (2*t+3)*64; \
    PHASE(0, 0, (STG_A(1,2,ko1), STG_A(1,3,ko1)), (void)0); \
    PHASE(0, 1, (STG_B(0,0,ko2,KD), STG_B(0,1,ko2,KD)), (void)0); \
    PHASE(0, 2, (STG_B(0,2,ko2,KD), STG_B(0,3,ko2,KD)), (void)0); \
    PHASE(0, 3, (STG_A(0,0,ko2), STG_A(0,1,ko2)), VMW(6)); \
    PHASE(1, 0, (STG_A(0,2,ko2), STG_A(0,3,ko2)), (void)0); \
    PHASE(1, 1, (STG_B(1,0,ko3,KD), STG_B(1,1,ko3,KD)), (void)0); \
    PHASE(1, 2, (STG_B(1,2,ko3,KD), STG_B(1,3,ko3,KD)), (void)0); \
    PHASE(1, 3, (STG_A(1,0,ko3), STG_A(1,1,ko3)), VMW(6)); \
  } \
  { \
    int ko1 = (2*(TT)-1)*64; \
    PHASE(0, 0, (STG_A(1,2,ko1), STG_A(1,3,ko1)), (void)0); \
    PHASE(0, 1, (void)0, (void)0); \
    PHASE(0, 2, (void)0, (void)0); \
    PHASE(0, 3, (void)0, VMW(0)); \
    PHASE(1, 0, (void)0, (void)0); \
    PHASE(1, 1, (void)0, (void)0); \
    PHASE(1, 2, (void)0, (void)0); \
    PHASE(1, 3, (void)0, (void)0); \
  } \
} while (0)

// ---------------- router: one wave per token, all fp32; fused x->bf16 cast ----------------
__global__ __launch_bounds__(256) void router_kernel(
    const float* __restrict__ x, const float* __restrict__ Wr,
    int* __restrict__ cnt, float* __restrict__ imp, float* __restrict__ z2,
    int* __restrict__ tke, float* __restrict__ tkw, ushort* __restrict__ xb)
{
  __shared__ float sWr[E_ * D_];
  __shared__ float bImp[E_];
  __shared__ float bZ2;
  __shared__ int bCnt[E_];
  int tid = threadIdx.x;
  for (int i = 0; i < 4; i++) {
    int d = tid + i * 256;
    float4 v0 = *(const float4*)(Wr + (size_t)d * E_);
    float4 v1 = *(const float4*)(Wr + (size_t)d * E_ + 4);
    sWr[0 * D_ + d] = v0.x; sWr[1 * D_ + d] = v0.y;
    sWr[2 * D_ + d] = v0.z; sWr[3 * D_ + d] = v0.w;
    sWr[4 * D_ + d] = v1.x; sWr[5 * D_ + d] = v1.y;
    sWr[6 * D_ + d] = v1.z; sWr[7 * D_ + d] = v1.w;
  }
  if (tid < E_) { bImp[tid] = 0.f; bCnt[tid] = 0; }
  if (tid == E_) bZ2 = 0.f;
  __syncthreads();

  int wave = tid >> 6, lane = tid & 63;
  int t = blockIdx.x * 4 + wave;
  const float* xr = x + (size_t)t * D_;
  float part[E_];
  for (int e = 0; e < E_; e++) part[e] = 0.f;
  for (int i = 0; i < 4; i++) {
    int d0 = i * 256 + lane * 4;
    float4 xv = *(const float4*)(xr + d0);
    if (xb) {
      ushort o[4] = {f2bf(xv.x), f2bf(xv.y), f2bf(xv.z), f2bf(xv.w)};
      *(uint2*)(xb + (size_t)t * D_ + d0) = *(const uint2*)o;
    }
    for (int e = 0; e < E_; e++)
      part[e] += xv.x * sWr[e * D_ + d0] + xv.y * sWr[e * D_ + d0 + 1] +
                 xv.z * sWr[e * D_ + d0 + 2] + xv.w * sWr[e * D_ + d0 + 3];
  }
  for (int sh = 32; sh >= 1; sh >>= 1)
    for (int e = 0; e < E_; e++)
      part[e] += __shfl_xor(part[e], sh, 64);

  // top-2, JAX tie semantics (first index wins)
  float v1 = part[0]; int i1 = 0;
  for (int e = 1; e < E_; e++) if (part[e] > v1) { v1 = part[e]; i1 = e; }
  float v2 = -3.4e38f; int i2 = 0;
  for (int e = 0; e < E_; e++) if (e != i1 && part[e] > v2) { v2 = part[e]; i2 = e; }
  float w1f = 1.f / (1.f + __expf(v2 - v1));
  float w2f = 1.f - w1f;

  float s = 0.f;
  float pr[E_];
  for (int e = 0; e < E_; e++) { float ex = __expf(part[e] - v1); pr[e] = ex; s += ex; }
  float inv = 1.f / s;
  float z = v1 + __logf(s);

  if (lane == 0) {
    tke[2 * t] = i1; tke[2 * t + 1] = i2;
    tkw[2 * t] = w1f; tkw[2 * t + 1] = w2f;
    for (int e = 0; e < E_; e++) atomicAdd(&bImp[e], pr[e] * inv);
    atomicAdd(&bZ2, z * z);
    atomicAdd(&bCnt[i1], 1);
    atomicAdd(&bCnt[i2], 1);
  }
  __syncthreads();
  if (tid < E_) { atomicAdd(&imp[tid], bImp[tid]); atomicAdd(&cnt[tid], bCnt[tid]); }
  if (tid == E_) atomicAdd(z2, bZ2);
}

// ---------------- finalize: offsets (256-aligned) + tail outputs ----------------
__global__ void finalize_kernel(const int* __restrict__ cnt, const float* __restrict__ imp,
                                const float* __restrict__ z2, int* __restrict__ off,
                                float* __restrict__ tail)
{
  if (threadIdx.x == 0 && blockIdx.x == 0) {
    int o = 0;
    for (int e = 0; e < E_; e++) { off[e] = o; o += ((cnt[e] + 255) & ~255); }
    off[E_] = o;
    for (int e = 0; e < E_; e++) tail[e] = (float)cnt[e];
    for (int e = 0; e < E_; e++) tail[E_ + e] = (float)cnt[e] / (float)NASSIGN;
    float sum2 = 0.f;
    for (int e = 0; e < E_; e++) { float p = imp[e] / (float)NTOK; sum2 += p * p; }
    float lb = 8.f * sum2 * 0.01f;
    float zl = (z2[0] / (float)NTOK) * 0.001f;
    tail[2 * E_] = lb + zl;
  }
}

// ------- scatter with LDS aggregation: 256 global atomics instead of 16384 -------
__global__ __launch_bounds__(256) void scatter_kernel(
    const int* __restrict__ tke, const int* __restrict__ off, int* __restrict__ fill,
    int* __restrict__ rowtok, int* __restrict__ tpos)
{
  __shared__ int lcnt[E_], lbase[E_];
  int tid = threadIdx.x;
  if (tid < E_) lcnt[tid] = 0;
  __syncthreads();
  int t = blockIdx.x * 256 + tid;
  int e0 = tke[2 * t], e1 = tke[2 * t + 1];
  int r0 = atomicAdd(&lcnt[e0], 1);
  int r1 = atomicAdd(&lcnt[e1], 1);
  __syncthreads();
  if (tid < E_) lbase[tid] = atomicAdd(&fill[tid], lcnt[tid]);
  __syncthreads();
  int p0 = off[e0] + lbase[e0] + r0;
  int p1 = off[e1] + lbase[e1] + r1;
  rowtok[p0] = t; rowtok[p1] = t;
  tpos[2 * t] = p0; tpos[2 * t + 1] = p1;
}

// ------- transpose+cast: dst(bf16)[z][c][r] = src(fp32)[z][r][c]; tile is [c][r] -------
__global__ __launch_bounds__(256) void transpose_cast_kernel(
    const float* __restrict__ src, ushort* __restrict__ dst, int R, int C)
{
  __shared__ float tile[64][68];   // [c-idx][r-idx], ld=68 (+4 pad)
  const float* s = src + (size_t)blockIdx.z * R * C;
  ushort* d = dst + (size_t)blockIdx.z * R * C;
  int c0 = blockIdx.x * 64, r0 = blockIdx.y * 64;
  int tid = threadIdx.x;
  {
    int row = tid >> 2;             // r-idx 0..63
    int col4 = (tid & 3) * 16;      // c-idx base
    const float* sp = s + (size_t)(r0 + row) * C + c0 + col4;
#pragma unroll
    for (int q = 0; q < 16; q++) tile[col4 + q][row] = sp[q];
  }
  __syncthreads();
  int tr8 = (tid & 7) * 8;
#pragma unroll
  for (int i = 0; i < 2; i++) {
    int cc = (tid >> 3) + i * 32;
    ushort tmp[8];
#pragma unroll
    for (int j = 0; j < 8; j++) tmp[j] = f2bf(tile[cc][tr8 + j]);
    *(uint4*)(d + (size_t)(c0 + cc) * R + r0 + tr8) = *(const uint4*)tmp;
  }
}

// ====== GEMM1 256x256 8-phase: H(bf16) = relu(gather(xb) @ W1bt^T + b1) ======
// CH capped at 8192 -> nx=32, grid 512 valid blocks = exactly 2 rounds.
__global__ __launch_bounds__(512, 2) void gemm1g_kernel(
    const ushort* __restrict__ xb, const ushort* __restrict__ W1bt,
    const float* __restrict__ b1, const int* __restrict__ rowtok,
    const int* __restrict__ off, ushort* __restrict__ H,
    int chunk_base, int nx)
{
  __shared__ ushort lds[65536];    // 128 KiB
  int per = (nx + 7) >> 3;
  int wid = blockIdx.x;
  int rest = wid >> 3;
  int bxi = rest % per;            // bx inner: B-panel slice stays L2-resident
  int y = rest / per;              // y outer
  int bx = (wid & 7) * per + bxi;  // XCD stripes
  if (bx >= nx) return;
  int row0 = chunk_base + bx * 256;
  int total = off[E_];
  if (row0 >= total) return;
  int e = 0;
  while (e < E_ - 1 && off[e + 1] <= row0) e++;
  int f0 = y * 256;
  int tid = threadIdx.x;
  int lane = tid & 63;
  int w8 = tid >> 6;
  int wm = w8 >> 2, wn = w8 & 3;
  int l15 = lane & 15, quad = (lane >> 4) & 3;

  // staging sources (pre-swizzled chunk so linear LDS dest holds swizzled tile)
  int t8 = tid & 255;
  int csA = (t8 & 7) ^ ((t8 >> 3) & 7);
  int csB = (tid & 7) ^ ((tid >> 3) & 7);
  const ushort* ap[4];
#pragma unroll
  for (int r = 0; r < 4; r++) {
    int rowA = (tid >> 8) * 128 + r * 32 + (t8 >> 3);
    int tok = rowtok[row0 + rowA];
    if (tok < 0) tok = 0;          // pad rows: finite garbage, never read
    ap[r] = xb + (size_t)tok * D_ + csA * 8;
  }
  const ushort* bpb = W1bt + ((size_t)e * F_ + f0 + (tid >> 3)) * D_ + csB * 8;
  int ahalf = (tid >> 8) * 8192;
  int alane = (tid & 192) * 8;
  int blane = (tid & 448) * 8;

  f32x4 acc[8][4];
  f32x4 zz = {0.f, 0.f, 0.f, 0.f};
#pragma unroll
  for (int i = 0; i < 8; i++)
#pragma unroll
    for (int j = 0; j < 4; j++) acc[i][j] = zz;
  short8 b[4][2];

  PROLOGUE(D_);
  EIGHT_PHASE_LOOP(8, D_);       // NT = 1024/64 = 16 tiles, T = 8 iters

  // epilogue: bias+relu, per-wave repack region (all accesses wave-local:
  // final phase's end-barrier already synced; reg rows/cols belong to this
  // wave's own 128x64 region), vec row stores
  float bv[4];
#pragma unroll
  for (int j = 0; j < 4; j++)
    bv[j] = b1[e * F_ + f0 + wn * 64 + j * 16 + l15];
  ushort* reg = lds + w8 * 8192;               // own 128x64 region per wave
#pragma unroll
  for (int i = 0; i < 8; i++) {
#pragma unroll
    for (int rg = 0; rg < 4; rg++) {
      int row = i * 16 + quad * 4 + rg;
#pragma unroll
      for (int j = 0; j < 4; j++) {
        float vv = acc[i][j][rg] + bv[j];
        vv = vv > 0.f ? vv : 0.f;
        int col = j * 16 + l15;
        reg[row * 64 + (((col >> 3) ^ (row & 7)) * 8) + (col & 7)] = f2bf(vv);
      }
    }
  }
  __builtin_amdgcn_s_barrier();   // wave-local LDS write -> read ordering (lgkm by HW on same wave; barrier for safety across scheduler)
  size_t hb = (size_t)(row0 - chunk_base) + (size_t)wm * 128;
#pragma unroll
  for (int ps = 0; ps < 2; ps++) {
    int row = ps * 64 + lane;
    ushort* dst = H + (hb + row) * F_ + f0 + wn * 64;
#pragma unroll
    for (int cc = 0; cc < 8; cc++)
      *(uint4*)(dst + cc * 8) = *(const uint4*)&reg[row * 64 + ((cc ^ (row & 7)) * 8)];
  }
}

// ====== GEMM2 256x256 8-phase split-K(4): Ya(f32) += H @ W2bt^T ======
// grid = 8 XCD * per * (ny=4 * ks=4); with nx=32 -> 512 valid = 2 exact rounds.
__global__ __launch_bounds__(512, 2) void gemm2g_kernel(
    const ushort* __restrict__ H, const ushort* __restrict__ W2bt,
    const int* __restrict__ off, float* __restrict__ Ya,
    int chunk_base, int nx)
{
  __shared__ ushort lds[65536];
  int per = (nx + 7) >> 3;
  int wid = blockIdx.x;
  int rest = wid >> 3;
  int bxi = rest % per;
  int tmp = rest / per;            // 0..15
  int y = tmp & 3;                 // ny = 4
  int ks = tmp >> 2;               // split-K quarter 0..3
  int bx = (wid & 7) * per + bxi;
  if (bx >= nx) return;
  int row0 = chunk_base + bx * 256;
  int total = off[E_];
  if (row0 >= total) return;
  int e = 0;
  while (e < E_ - 1 && off[e + 1] <= row0) e++;
  int d0 = y * 256;
  int tid = threadIdx.x;
  int lane = tid & 63;
  int w8 = tid >> 6;
  int wm = w8 >> 2, wn = w8 & 3;
  int l15 = lane & 15, quad = (lane >> 4) & 3;

  int ksbase = ks * 1024;
  int t8 = tid & 255;
  int csA = (t8 & 7) ^ ((t8 >> 3) & 7);
  int csB = (tid & 7) ^ ((tid >> 3) & 7);
  const ushort* ap[4];
#pragma unroll
  for (int r = 0; r < 4; r++) {
    int rowA = (tid >> 8) * 128 + r * 32 + (t8 >> 3);
    ap[r] = H + (size_t)(bx * 256 + rowA) * F_ + ksbase + csA * 8;
  }
  const ushort* bpb = W2bt + ((size_t)e * D_ + d0 + (tid >> 3)) * F_ + ksbase + csB * 8;
  int ahalf = (tid >> 8) * 8192;
  int alane = (tid & 192) * 8;
  int blane = (tid & 448) * 8;

  f32x4 acc[8][4];
  f32x4 zz = {0.f, 0.f, 0.f, 0.f};
#pragma unroll
  for (int i = 0; i < 8; i++)
#pragma unroll
    for (int j = 0; j < 4; j++) acc[i][j] = zz;
  short8 b[4][2];

  PROLOGUE(F_);
  EIGHT_PHASE_LOOP(8, F_);       // 1024/64 = 16 tiles per K-quarter, T = 8

  // epilogue: f32 atomic add (exactly 4 contributions per element onto zeroed Ya)
#pragma unroll
  for (int i = 0; i < 8; i++) {
    int mrow = wm * 128 + i * 16 + quad * 4;
#pragma unroll
    for (int rg = 0; rg < 4; rg++) {
      size_t base = (size_t)(row0 + mrow + rg) * D_ + d0;
#pragma unroll
      for (int j = 0; j < 4; j++) {
        int cc = wn * 64 + j * 16 + l15;
        atomicAdd(Ya + base + cc, acc[i][j][rg]);
      }
    }
  }
}

// ============ fallback GEMMs (validated round-2 code), used only if ws is small ============
template<bool XB, bool BT>
__global__ __launch_bounds__(256) void gemm1_kernel(
    const float* __restrict__ x, const ushort* __restrict__ xb,
    const ushort* __restrict__ W1bt, const float* __restrict__ W1nat,
    const float* __restrict__ b1, const int* __restrict__ rowtok,
    const int* __restrict__ off, ushort* __restrict__ H, int chunk_base)
{
  __shared__ ushort As[128 * 72];
  __shared__ ushort Bs[128 * 72];
  int row0 = chunk_base + blockIdx.x * 128;
  int total = off[E_];
  if (row0 >= total) return;
  int e = 0;
  while (e < E_ - 1 && off[e + 1] <= row0) e++;
  int f0 = blockIdx.y * 128;
  int tid = threadIdx.x;
  int wave = tid >> 6, lane = tid & 63;
  int wm = wave & 1, wn = wave >> 1;
  int l15 = lane & 15, quad = lane >> 4;

  int r = tid >> 1, h = tid & 1;
  int tokA = rowtok[row0 + r];
  size_t aoff = ((tokA >= 0) ? (size_t)tokA * D_ : 0) + h * 32;

  f32x4 acc[4][4];
  f32x4 zz = {0.f, 0.f, 0.f, 0.f};
  for (int i = 0; i < 4; i++) for (int j = 0; j < 4; j++) acc[i][j] = zz;

  for (int k0 = 0; k0 < D_; k0 += 64) {
    for (int q = 0; q < 4; q++) {
      uint4 v;
      if (tokA >= 0) {
        if (XB) {
          v = *(const uint4*)(xb + aoff + k0 + q * 8);
        } else {
          float4 fa = *(const float4*)(x + aoff + k0 + q * 8);
          float4 fb = *(const float4*)(x + aoff + k0 + q * 8 + 4);
          ushort t8[8] = {f2bf(fa.x), f2bf(fa.y), f2bf(fa.z), f2bf(fa.w),
                          f2bf(fb.x), f2bf(fb.y), f2bf(fb.z), f2bf(fb.w)};
          v = *(const uint4*)t8;
        }
      } else v = make_uint4(0u, 0u, 0u, 0u);
      *(uint4*)&As[r * 72 + h * 32 + q * 8] = v;
    }
    if (BT) {
      const ushort* bs = W1bt + ((size_t)e * F_ + f0 + r) * D_ + k0 + h * 32;
      for (int q = 0; q < 4; q++)
        *(uint4*)&Bs[r * 72 + h * 32 + q * 8] = *(const uint4*)(bs + q * 8);
    } else {
      for (int i = 0; i < 8; i++) {
        int c = tid + i * 256;
        int kk = c >> 5;
        int n4 = (c & 31) * 4;
        float4 v = *(const float4*)(W1nat + (size_t)e * D_ * F_ +
                                    (size_t)(k0 + kk) * F_ + f0 + n4);
        Bs[(n4 + 0) * 72 + kk] = f2bf(v.x);
        Bs[(n4 + 1) * 72 + kk] = f2bf(v.y);
        Bs[(n4 + 2) * 72 + kk] = f2bf(v.z);
        Bs[(n4 + 3) * 72 + kk] = f2bf(v.w);
      }
    }
    __syncthreads();
    for (int s = 0; s < 2; s++) {
      int kc = s * 32 + quad * 8;
      short8 a[4], b[4];
      for (int i = 0; i < 4; i++)
        a[i] = *(const short8*)&As[(wm * 64 + i * 16 + l15) * 72 + kc];
      for (int j = 0; j < 4; j++)
        b[j] = *(const short8*)&Bs[(wn * 64 + j * 16 + l15) * 72 + kc];
      for (int i = 0; i < 4; i++)
        for (int j = 0; j < 4; j++)
          acc[i][j] = mfma16(a[i], b[j], acc[i][j]);
    }
    __syncthreads();
  }

  float bv[4];
  for (int j = 0; j < 4; j++)
    bv[j] = b1[e * F_ + f0 + wn * 64 + j * 16 + l15];
  ushort* Hb = H + (size_t)(row0 - chunk_base) * F_;
  for (int i = 0; i < 4; i++) {
    int mrow = wm * 64 + i * 16 + quad * 4;
    for (int rg = 0; rg < 4; rg++) {
      ushort* dst = Hb + (size_t)(mrow + rg) * F_ + f0;
      for (int j = 0; j < 4; j++) {
        float vv = acc[i][j][rg] + bv[j];
        vv = vv > 0.f ? vv : 0.f;
        dst[wn * 64 + j * 16 + l15] = f2bf(vv);
      }
    }
  }
}

template<bool YF32>
__global__ __launch_bounds__(256) void gemm2_kernel(
    const ushort* __restrict__ H, const float* __restrict__ W2nat,
    const int* __restrict__ off, void* __restrict__ Ya, int chunk_base)
{
  __shared__ ushort As[128 * 72];
  __shared__ ushort Bs[128 * 72];
  int row0 = chunk_base + blockIdx.x * 128;
  int total = off[E_];
  if (row0 >= total) return;
  int e = 0;
  while (e < E_ - 1 && off[e + 1] <= row0) e++;
  int d0 = blockIdx.y * 128;
  int tid = threadIdx.x;
  int wave = tid >> 6, lane = tid & 63;
  int wm = wave & 1, wn = wave >> 1;
  int l15 = lane & 15, quad = lane >> 4;

  int r = tid >> 1, h = tid & 1;
  const ushort* aSrc = H + (size_t)(blockIdx.x * 128 + r) * F_ + h * 32;

  f32x4 acc[4][4];
  f32x4 zz = {0.f, 0.f, 0.f, 0.f};
  for (int i = 0; i < 4; i++) for (int j = 0; j < 4; j++) acc[i][j] = zz;

  for (int k0 = 0; k0 < F_; k0 += 64) {
    for (int q = 0; q < 4; q++)
      *(uint4*)&As[r * 72 + h * 32 + q * 8] = *(const uint4*)(aSrc + k0 + q * 8);
    for (int i = 0; i < 8; i++) {
      int c = tid + i * 256;
      int kk = c >> 5;
      int n4 = (c & 31) * 4;
      float4 v = *(const float4*)(W2nat + (size_t)e * F_ * D_ +
                                  (size_t)(k0 + kk) * D_ + d0 + n4);
      Bs[(n4 + 0) * 72 + kk] = f2bf(v.x);
      Bs[(n4 + 1) * 72 + kk] = f2bf(v.y);
      Bs[(n4 + 2) * 72 + kk] = f2bf(v.z);
      Bs[(n4 + 3) * 72 + kk] = f2bf(v.w);
    }
    __syncthreads();
    for (int s = 0; s < 2; s++) {
      int kc = s * 32 + quad * 8;
      short8 a[4], b[4];
      for (int i = 0; i < 4; i++)
        a[i] = *(const short8*)&As[(wm * 64 + i * 16 + l15) * 72 + kc];
      for (int j = 0; j < 4; j++)
        b[j] = *(const short8*)&Bs[(wn * 64 + j * 16 + l15) * 72 + kc];
      for (int i = 0; i < 4; i++)
        for (int j = 0; j < 4; j++)
          acc[i][j] = mfma16(a[i], b[j], acc[i][j]);
    }
    __syncthreads();
  }

  for (int i = 0; i < 4; i++) {
    int mrow = wm * 64 + i * 16 + quad * 4;
    for (int rg = 0; rg < 4; rg++) {
      size_t base = (size_t)(row0 + mrow + rg) * D_ + d0;
      for (int j = 0; j < 4; j++) {
        int cc = wn * 64 + j * 16 + l15;
        if (YF32) ((float*)Ya)[base + cc] = acc[i][j][rg];
        else ((ushort*)Ya)[base + cc] = f2bf(acc[i][j][rg]);
      }
    }
  }
}

// -------- combine: y[t] = w0*(Ya[p0]+b2[e0]) + w1*(Ya[p1]+b2[e1]) --------
template<bool YF32>
__global__ __launch_bounds__(256) void combine_kernel(
    const void* __restrict__ Ya, const float* __restrict__ b2,
    const int* __restrict__ tpos, const int* __restrict__ tke,
    const float* __restrict__ tkw, float* __restrict__ y)
{
  int t = blockIdx.x;
  int c = threadIdx.x * 4;
  int p0 = tpos[2 * t], p1 = tpos[2 * t + 1];
  int e0 = tke[2 * t], e1 = tke[2 * t + 1];
  float w0 = tkw[2 * t], w1 = tkw[2 * t + 1];
  float a0[4], a1[4];
  if (YF32) {
    float4 va = *(const float4*)((const float*)Ya + (size_t)p0 * D_ + c);
    float4 vb = *(const float4*)((const float*)Ya + (size_t)p1 * D_ + c);
    a0[0] = va.x; a0[1] = va.y; a0[2] = va.z; a0[3] = va.w;
    a1[0] = vb.x; a1[1] = vb.y; a1[2] = vb.z; a1[3] = vb.w;
  } else {
    uint2 ua = *(const uint2*)((const ushort*)Ya + (size_t)p0 * D_ + c);
    uint2 ub = *(const uint2*)((const ushort*)Ya + (size_t)p1 * D_ + c);
    const ushort* pa = (const ushort*)&ua;
    const ushort* pb = (const ushort*)&ub;
    for (int q = 0; q < 4; q++) {
      a0[q] = __uint_as_float(((uint32_t)pa[q]) << 16);
      a1[q] = __uint_as_float(((uint32_t)pb[q]) << 16);
    }
  }
  float4 vb0 = *(const float4*)(b2 + (size_t)e0 * D_ + c);
  float4 vb1 = *(const float4*)(b2 + (size_t)e1 * D_ + c);
  float4 o;
  o.x = w0 * (a0[0] + vb0.x) + w1 * (a1[0] + vb1.x);
  o.y = w0 * (a0[1] + vb0.y) + w1 * (a1[1] + vb1.y);
  o.z = w0 * (a0[2] + vb0.z) + w1 * (a1[2] + vb1.z);
  o.w = w0 * (a0[3] + vb0.w) + w1 * (a1[3] + vb1.w);
  *(float4*)(y + (size_t)t * D_ + c) = o;
}

extern "C" void kernel_launch(void* const* d_in, const int* in_sizes, int n_in,
                              void* d_out, int out_size, void* d_ws, size_t ws_size,
                              hipStream_t stream) {
  (void)in_sizes; (void)n_in; (void)out_size;
  const float* x  = (const float*)d_in[0];
  const float* Wr = (const float*)d_in[1];
  const float* W1 = (const float*)d_in[2];
  const float* b1 = (const float*)d_in[3];
  const float* W2 = (const float*)d_in[4];
  const float* b2 = (const float*)d_in[5];
  float* out = (float*)d_out;

  char* ws = (char*)d_ws;
  int*   cnt    = (int*)(ws + 0);
  int*   fill   = (int*)(ws + 32);
  float* imp    = (float*)(ws + 64);
  float* z2     = (float*)(ws + 96);
  int*   off    = (int*)(ws + 128);
  int*   tke    = (int*)(ws + 256);
  float* tkw    = (float*)(ws + 256 + 65536);
  int*   tpos   = (int*)(ws + 256 + 2 * 65536);
  int*   rowtok = (int*)(ws + 256 + 3 * 65536);
  size_t p = 256 + 3 * 65536 + (size_t)CAP * 4;
  p = (p + 4095) & ~(size_t)4095;

  const size_t XB_SZ = (size_t)NTOK * D_ * 2;          // 16.8 MB
  const size_t YA32  = (size_t)CAP * D_ * 4;           // 75.5 MB
  const size_t YA16  = (size_t)CAP * D_ * 2;           // 37.7 MB
  const size_t WT    = (size_t)E_ * D_ * F_ * 2;       // 67.1 MB
  const size_t HROW  = (size_t)F_ * 2;
  const size_t MINH  = 256 * HROW;                     // 2 MB

  bool xb_on = true, ya32 = true;
  if (ws_size < p + XB_SZ + YA32 + MINH) {
    ya32 = false;
    if (ws_size < p + XB_SZ + YA16 + MINH) xb_on = false;
  }
  ushort* xb = nullptr;
  if (xb_on) { xb = (ushort*)(ws + p); p += XB_SZ; }
  void* Ya = (void*)(ws + p);
  p += ya32 ? YA32 : YA16;

  bool w1t_on = false, w2t_on = false;
  ushort* W1bt = nullptr; ushort* W2bt = nullptr;
  if (ws_size >= p + WT + MINH) { w1t_on = true; W1bt = (ushort*)(ws + p); p += WT; }
  if (ws_size >= p + WT + MINH) { w2t_on = true; W2bt = (ushort*)(ws + p); p += WT; }

  size_t hav = ws_size > p ? ws_size - p : 0;
  long long chl = (long long)(hav / HROW);
  int CH = (int)(chl & ~255LL);
  if (CH < 256) CH = 256;
  if (CH > 8192) CH = 8192;   // exact-packing cap: nx=32 -> g1 512blk=2 rounds, g2 512blk=2 rounds
  ushort* Hbuf = (ushort*)(ws + p);
  int nchunks = (CAP + CH - 1) / CH;

  bool g1fast = xb_on && w1t_on;
  bool g2fast = w2t_on && ya32;

  hipMemsetAsync(ws, 0, 128, stream);
  hipMemsetAsync(rowtok, 0xFF, (size_t)CAP * 4, stream);
  if (g2fast) hipMemsetAsync(Ya, 0, YA32, stream);   // split-K accumulates
  router_kernel<<<NTOK / 4, 256, 0, stream>>>(x, Wr, cnt, imp, z2, tke, tkw, xb);
  finalize_kernel<<<1, 64, 0, stream>>>(cnt, imp, z2, off, out + (size_t)NTOK * D_);
  scatter_kernel<<<NTOK / 256, 256, 0, stream>>>(tke, off, fill, rowtok, tpos);
  if (w1t_on)
    transpose_cast_kernel<<<dim3(F_ / 64, D_ / 64, E_), 256, 0, stream>>>(W1, W1bt, D_, F_);
  if (w2t_on)
    transpose_cast_kernel<<<dim3(D_ / 64, F_ / 64, E_), 256, 0, stream>>>(W2, W2bt, F_, D_);

  for (int c = 0; c < nchunks; c++) {
    int cb = c * CH;
    int nxc = CH / 256;
    int perx = (nxc + 7) >> 3;
    if (g1fast) {
      gemm1g_kernel<<<8 * perx * 16, 512, 0, stream>>>(xb, W1bt, b1, rowtok, off, Hbuf, cb, nxc);
    } else {
      dim3 g1(CH / 128, F_ / 128);
      if (xb_on) gemm1_kernel<true, false><<<g1, 256, 0, stream>>>(x, xb, W1bt, W1, b1, rowtok, off, Hbuf, cb);
      else       gemm1_kernel<false, false><<<g1, 256, 0, stream>>>(x, xb, W1bt, W1, b1, rowtok, off, Hbuf, cb);
    }
    if (g2fast) {
      gemm2g_kernel<<<8 * perx * 16, 512, 0, stream>>>(Hbuf, W2bt, off, (float*)Ya, cb, nxc);
    } else {
      dim3 g2(CH / 128, D_ / 128);
      if (ya32) gemm2_kernel<true><<<g2, 256, 0, stream>>>(Hbuf, W2, off, Ya, cb);
      else      gemm2_kernel<false><<<g2, 256, 0, stream>>>(Hbuf, W2, off, Ya, cb);
    }
  }
  if (ya32) combine_kernel<true><<<NTOK, 256, 0, stream>>>(Ya, b2, tpos, tke, tkw, out);
  else      combine_kernel<false><<<NTOK, 256, 0, stream>>>(Ya, b2, tpos, tke, tkw, out);
}

// Round 6
// 815.387 us; speedup vs baseline: 1.2482x; 1.2482x over previous
//
#include <hip/hip_runtime.h>
#include <stdint.h>

#define E_ 8
#define D_ 1024
#define F_ 4096
#define NTOK 8192
#define NASSIGN 16384
#define CAP 18432   // 16384 + 8*256 worst-case padding, multiple of 256

typedef __attribute__((ext_vector_type(8))) short short8;
typedef __attribute__((ext_vector_type(8))) __bf16 bf16x8;
typedef __attribute__((ext_vector_type(4))) float f32x4;

__device__ __forceinline__ ushort f2bf(float f) {
  uint32_t u = __float_as_uint(f);
  uint32_t r = (u + 0x7fffu + ((u >> 16) & 1u)) >> 16;
  return (ushort)r;
}

__device__ __forceinline__ f32x4 mfma16(short8 a, short8 b, f32x4 c) {
  return __builtin_amdgcn_mfma_f32_16x16x32_bf16(
      __builtin_bit_cast(bf16x8, a), __builtin_bit_cast(bf16x8, b), c, 0, 0, 0);
}

// async global->LDS, 16B per lane. LDS dest is wave-uniform base + lane*16.
__device__ __forceinline__ void gld16(const ushort* g, ushort* l) {
  __builtin_amdgcn_global_load_lds(
      (const __attribute__((address_space(1))) unsigned int*)(const void*)g,
      (__attribute__((address_space(3))) unsigned int*)(void*)l, 16, 0, 0);
}

// ============ 128x256 BK=32 GEMM core, 2 blocks/CU ============
// LDS per block 48KB loop-active: buf{0,1} x (A 4096 ush | B 8192 ush),
// stride 12288 ushorts. Tile rows x 4 chunks of 16B; physical slot s of row r
// holds logical k-chunk s ^ ((r>>1)&3)  (2-way bank aliasing = free, m136).
// Staging: linear LDS dest + pre-swizzled global source.
// Per iter: 8 ds_read_b128, lgkm(0) [reads complete], barrier [all waves'
// reads complete -> overwrite safe], stage tile t+2 into freed buf (3 loads),
// 16 MFMA, vmcnt(3) [t+1 staged, t+2 in flight] BEFORE barrier (vmcnt is
// per-wave; the barrier makes completion cross-wave-visible).
// Prologue: stage t0,t1 (6 loads), VMW(3) [t0 done], barrier.

#define RD32(BASE, R) \
  (*(const short8*)&lds[(BASE) + ((R) * 4 + (quad ^ (((R) >> 1) & 3))) * 8])

#define G_ITER(CUR, DOSTG, KO, VMWN) do { \
  short8 a0, a1, a2, a3, b0, b1, b2, b3; \
  { int ab = (CUR) * 12288, bb = ab + 4096; int r; \
    r = wm * 64 + l15;      a0 = RD32(ab, r); \
    r = wm * 64 + 16 + l15; a1 = RD32(ab, r); \
    r = wm * 64 + 32 + l15; a2 = RD32(ab, r); \
    r = wm * 64 + 48 + l15; a3 = RD32(ab, r); \
    r = wn * 64 + l15;      b0 = RD32(bb, r); \
    r = wn * 64 + 16 + l15; b1 = RD32(bb, r); \
    r = wn * 64 + 32 + l15; b2 = RD32(bb, r); \
    r = wn * 64 + 48 + l15; b3 = RD32(bb, r); } \
  asm volatile("s_waitcnt lgkmcnt(0)" ::: "memory"); \
  __builtin_amdgcn_sched_barrier(0); \
  __builtin_amdgcn_s_barrier(); \
  __builtin_amdgcn_sched_barrier(0); \
  if (DOSTG) { \
    gld16(apA + (KO), &lds[(CUR) * 12288 + ldA]); \
    gld16(bp0 + (KO), &lds[(CUR) * 12288 + ldB0]); \
    gld16(bp1 + (KO), &lds[(CUR) * 12288 + ldB1]); \
  } \
  __builtin_amdgcn_s_setprio(1); \
  acc[0][0] = mfma16(a0, b0, acc[0][0]); acc[0][1] = mfma16(a0, b1, acc[0][1]); \
  acc[0][2] = mfma16(a0, b2, acc[0][2]); acc[0][3] = mfma16(a0, b3, acc[0][3]); \
  acc[1][0] = mfma16(a1, b0, acc[1][0]); acc[1][1] = mfma16(a1, b1, acc[1][1]); \
  acc[1][2] = mfma16(a1, b2, acc[1][2]); acc[1][3] = mfma16(a1, b3, acc[1][3]); \
  acc[2][0] = mfma16(a2, b0, acc[2][0]); acc[2][1] = mfma16(a2, b1, acc[2][1]); \
  acc[2][2] = mfma16(a2, b2, acc[2][2]); acc[2][3] = mfma16(a2, b3, acc[2][3]); \
  acc[3][0] = mfma16(a3, b0, acc[3][0]); acc[3][1] = mfma16(a3, b1, acc[3][1]); \
  acc[3][2] = mfma16(a3, b2, acc[3][2]); acc[3][3] = mfma16(a3, b3, acc[3][3]); \
  __builtin_amdgcn_s_setprio(0); \
  asm volatile("s_waitcnt vmcnt(" #VMWN ")" ::: "memory"); \
  __builtin_amdgcn_sched_barrier(0); \
  __builtin_amdgcn_s_barrier(); \
  __builtin_amdgcn_sched_barrier(0); \
} while (0)

#define G_PROLOGUE() do { \
  gld16(apA,      &lds[ldA]);          gld16(bp0,      &lds[ldB0]); \
  gld16(bp1,      &lds[ldB1]); \
  gld16(apA + 32, &lds[12288 + ldA]);  gld16(bp0 + 32, &lds[12288 + ldB0]); \
  gld16(bp1 + 32, &lds[12288 + ldB1]); \
  asm volatile("s_waitcnt vmcnt(3)" ::: "memory"); \
  __builtin_amdgcn_sched_barrier(0); \
  __builtin_amdgcn_s_barrier(); \
  __builtin_amdgcn_sched_barrier(0); \
} while (0)

#define G_LOOP(NK) do { \
  _Pragma("unroll 1") \
  for (int t = 0; t < (NK) - 2; t += 2) { \
    int ko2 = (t + 2) * 32, ko3 = (t + 3) * 32; \
    G_ITER(0, 1, ko2, 3); \
    G_ITER(1, 1, ko3, 3); \
  } \
  G_ITER(0, 0, 0, 0); \
  G_ITER(1, 0, 0, 0); \
} while (0)

// ---------------- router: one wave per token, all fp32; fused x->bf16 cast ----------------
__global__ __launch_bounds__(256) void router_kernel(
    const float* __restrict__ x, const float* __restrict__ Wr,
    int* __restrict__ cnt, float* __restrict__ imp, float* __restrict__ z2,
    int* __restrict__ tke, float* __restrict__ tkw, ushort* __restrict__ xb)
{
  __shared__ float sWr[E_ * D_];
  __shared__ float bImp[E_];
  __shared__ float bZ2;
  __shared__ int bCnt[E_];
  int tid = threadIdx.x;
  for (int i = 0; i < 4; i++) {
    int d = tid + i * 256;
    float4 v0 = *(const float4*)(Wr + (size_t)d * E_);
    float4 v1 = *(const float4*)(Wr + (size_t)d * E_ + 4);
    sWr[0 * D_ + d] = v0.x; sWr[1 * D_ + d] = v0.y;
    sWr[2 * D_ + d] = v0.z; sWr[3 * D_ + d] = v0.w;
    sWr[4 * D_ + d] = v1.x; sWr[5 * D_ + d] = v1.y;
    sWr[6 * D_ + d] = v1.z; sWr[7 * D_ + d] = v1.w;
  }
  if (tid < E_) { bImp[tid] = 0.f; bCnt[tid] = 0; }
  if (tid == E_) bZ2 = 0.f;
  __syncthreads();

  int wave = tid >> 6, lane = tid & 63;
  int t = blockIdx.x * 4 + wave;
  const float* xr = x + (size_t)t * D_;
  float part[E_];
  for (int e = 0; e < E_; e++) part[e] = 0.f;
  for (int i = 0; i < 4; i++) {
    int d0 = i * 256 + lane * 4;
    float4 xv = *(const float4*)(xr + d0);
    if (xb) {
      ushort o[4] = {f2bf(xv.x), f2bf(xv.y), f2bf(xv.z), f2bf(xv.w)};
      *(uint2*)(xb + (size_t)t * D_ + d0) = *(const uint2*)o;
    }
    for (int e = 0; e < E_; e++)
      part[e] += xv.x * sWr[e * D_ + d0] + xv.y * sWr[e * D_ + d0 + 1] +
                 xv.z * sWr[e * D_ + d0 + 2] + xv.w * sWr[e * D_ + d0 + 3];
  }
  for (int sh = 32; sh >= 1; sh >>= 1)
    for (int e = 0; e < E_; e++)
      part[e] += __shfl_xor(part[e], sh, 64);

  // top-2, JAX tie semantics (first index wins)
  float v1 = part[0]; int i1 = 0;
  for (int e = 1; e < E_; e++) if (part[e] > v1) { v1 = part[e]; i1 = e; }
  float v2 = -3.4e38f; int i2 = 0;
  for (int e = 0; e < E_; e++) if (e != i1 && part[e] > v2) { v2 = part[e]; i2 = e; }
  float w1f = 1.f / (1.f + __expf(v2 - v1));
  float w2f = 1.f - w1f;

  float s = 0.f;
  float pr[E_];
  for (int e = 0; e < E_; e++) { float ex = __expf(part[e] - v1); pr[e] = ex; s += ex; }
  float inv = 1.f / s;
  float z = v1 + __logf(s);

  if (lane == 0) {
    tke[2 * t] = i1; tke[2 * t + 1] = i2;
    tkw[2 * t] = w1f; tkw[2 * t + 1] = w2f;
    for (int e = 0; e < E_; e++) atomicAdd(&bImp[e], pr[e] * inv);
    atomicAdd(&bZ2, z * z);
    atomicAdd(&bCnt[i1], 1);
    atomicAdd(&bCnt[i2], 1);
  }
  __syncthreads();
  if (tid < E_) { atomicAdd(&imp[tid], bImp[tid]); atomicAdd(&cnt[tid], bCnt[tid]); }
  if (tid == E_) atomicAdd(z2, bZ2);
}

// ---------------- finalize: offsets (256-aligned) + tail outputs ----------------
__global__ void finalize_kernel(const int* __restrict__ cnt, const float* __restrict__ imp,
                                const float* __restrict__ z2, int* __restrict__ off,
                                float* __restrict__ tail)
{
  if (threadIdx.x == 0 && blockIdx.x == 0) {
    int o = 0;
    for (int e = 0; e < E_; e++) { off[e] = o; o += ((cnt[e] + 255) & ~255); }
    off[E_] = o;
    for (int e = 0; e < E_; e++) tail[e] = (float)cnt[e];
    for (int e = 0; e < E_; e++) tail[E_ + e] = (float)cnt[e] / (float)NASSIGN;
    float sum2 = 0.f;
    for (int e = 0; e < E_; e++) { float p = imp[e] / (float)NTOK; sum2 += p * p; }
    float lb = 8.f * sum2 * 0.01f;
    float zl = (z2[0] / (float)NTOK) * 0.001f;
    tail[2 * E_] = lb + zl;
  }
}

// ------- scatter with LDS aggregation: 256 global atomics instead of 16384 -------
__global__ __launch_bounds__(256) void scatter_kernel(
    const int* __restrict__ tke, const int* __restrict__ off, int* __restrict__ fill,
    int* __restrict__ rowtok, int* __restrict__ tpos)
{
  __shared__ int lcnt[E_], lbase[E_];
  int tid = threadIdx.x;
  if (tid < E_) lcnt[tid] = 0;
  __syncthreads();
  int t = blockIdx.x * 256 + tid;
  int e0 = tke[2 * t], e1 = tke[2 * t + 1];
  int r0 = atomicAdd(&lcnt[e0], 1);
  int r1 = atomicAdd(&lcnt[e1], 1);
  __syncthreads();
  if (tid < E_) lbase[tid] = atomicAdd(&fill[tid], lcnt[tid]);
  __syncthreads();
  int p0 = off[e0] + lbase[e0] + r0;
  int p1 = off[e1] + lbase[e1] + r1;
  rowtok[p0] = t; rowtok[p1] = t;
  tpos[2 * t] = p0; tpos[2 * t + 1] = p1;
}

// ------- transpose+cast: dst(bf16)[z][c][r] = src(fp32)[z][r][c]; tile is [c][r] -------
__global__ __launch_bounds__(256) void transpose_cast_kernel(
    const float* __restrict__ src, ushort* __restrict__ dst, int R, int C)
{
  __shared__ float tile[64][68];   // [c-idx][r-idx], ld=68 (+4 pad)
  const float* s = src + (size_t)blockIdx.z * R * C;
  ushort* d = dst + (size_t)blockIdx.z * R * C;
  int c0 = blockIdx.x * 64, r0 = blockIdx.y * 64;
  int tid = threadIdx.x;
  {
    int row = tid >> 2;             // r-idx 0..63
    int col4 = (tid & 3) * 16;      // c-idx base
    const float* sp = s + (size_t)(r0 + row) * C + c0 + col4;
#pragma unroll
    for (int q = 0; q < 16; q++) tile[col4 + q][row] = sp[q];
  }
  __syncthreads();
  int tr8 = (tid & 7) * 8;
#pragma unroll
  for (int i = 0; i < 2; i++) {
    int cc = (tid >> 3) + i * 32;
    ushort tmp[8];
#pragma unroll
    for (int j = 0; j < 8; j++) tmp[j] = f2bf(tile[cc][tr8 + j]);
    *(uint4*)(d + (size_t)(c0 + cc) * R + r0 + tr8) = *(const uint4*)tmp;
  }
}

// ====== GEMM1 128x256 BK=32, 2 blocks/CU: H = relu(gather(xb) @ W1bt^T + b1) ======
__global__ __launch_bounds__(512, 4) void gemm1g_kernel(
    const ushort* __restrict__ xb, const ushort* __restrict__ W1bt,
    const float* __restrict__ b1, const int* __restrict__ rowtok,
    const int* __restrict__ off, ushort* __restrict__ H,
    int chunk_base, int mt)
{
  __shared__ ushort lds[32768];    // 64KB; loop uses 24576 ush, epilogue uses all
  int per = (mt + 7) >> 3;
  int wid = blockIdx.x;
  int rest = wid >> 3;
  int bxi = rest % per;            // bx inner: B-panel slice L2-resident
  int y = rest / per;              // 0..15 (F tiles of 256)
  int bx = (wid & 7) * per + bxi;  // XCD stripes
  if (bx >= mt) return;
  int row0 = chunk_base + bx * 128;
  int total = off[E_];
  if (row0 >= total) return;
  int e = 0;
  while (e < E_ - 1 && off[e + 1] <= row0) e++;
  int f0 = y * 256;
  int tid = threadIdx.x;
  int lane = tid & 63;
  int w8 = tid >> 6;
  int wm = w8 >> 2, wn = w8 & 3;   // 2x4 waves -> 128x256
  int l15 = lane & 15, quad = (lane >> 4) & 3;

  // staging sources (pre-swizzled chunk), ushort offsets
  int arow = tid >> 2, asl = tid & 3;
  int csA = asl ^ ((arow >> 1) & 3);
  int tok = rowtok[row0 + arow]; if (tok < 0) tok = 0;  // pad rows: finite garbage
  const ushort* apA = xb + (size_t)tok * D_ + csA * 8;
  int br1 = 128 + arow;
  int csB0 = asl ^ ((arow >> 1) & 3);
  int csB1 = asl ^ ((br1 >> 1) & 3);
  const ushort* bp0 = W1bt + ((size_t)e * F_ + f0 + arow) * D_ + csB0 * 8;
  const ushort* bp1 = W1bt + ((size_t)e * F_ + f0 + br1) * D_ + csB1 * 8;
  int ldA  = (tid & 448) * 8;
  int ldB0 = 4096 + (tid & 448) * 8;
  int ldB1 = 8192 + (tid & 448) * 8;

  f32x4 acc[4][4];
  f32x4 zz = {0.f, 0.f, 0.f, 0.f};
#pragma unroll
  for (int i = 0; i < 4; i++)
#pragma unroll
    for (int j = 0; j < 4; j++) acc[i][j] = zz;

  G_PROLOGUE();
  G_LOOP(32);          // D=1024 / 32

  // epilogue: bias+relu, wave-private 64x64 repack (swizzled), vec row stores
  float bv[4];
#pragma unroll
  for (int j = 0; j < 4; j++)
    bv[j] = b1[e * F_ + f0 + wn * 64 + j * 16 + l15];
  ushort* reg = lds + w8 * 4096;   // own 64x64 region per wave (8 x 8KB = 64KB)
#pragma unroll
  for (int i = 0; i < 4; i++) {
#pragma unroll
    for (int rg = 0; rg < 4; rg++) {
      int row = i * 16 + quad * 4 + rg;
#pragma unroll
      for (int j = 0; j < 4; j++) {
        float vv = acc[i][j][rg] + bv[j];
        vv = vv > 0.f ? vv : 0.f;
        int col = j * 16 + l15;
        reg[row * 64 + (((col >> 3) ^ (row & 7)) * 8) + (col & 7)] = f2bf(vv);
      }
    }
  }
  // wave-local write->read (compiler inserts lgkm waits)
  {
    int row = lane;                // 64 rows, one per lane
    ushort* dst = H + (size_t)(row0 - chunk_base + wm * 64 + row) * F_ + f0 + wn * 64;
#pragma unroll
    for (int cc = 0; cc < 8; cc++)
      *(uint4*)(dst + cc * 8) = *(const uint4*)&reg[row * 64 + ((cc ^ (row & 7)) * 8)];
  }
}

// ====== GEMM2 128x256 BK=32 split-K(2), 2 blocks/CU: Ya(f32) += H @ W2bt^T ======
__global__ __launch_bounds__(512, 4) void gemm2g_kernel(
    const ushort* __restrict__ H, const ushort* __restrict__ W2bt,
    const int* __restrict__ off, float* __restrict__ Ya,
    int chunk_base, int mt)
{
  __shared__ ushort lds[24576];    // 48KB loop-only
  int per = (mt + 7) >> 3;
  int wid = blockIdx.x;
  int rest = wid >> 3;
  int bxi = rest % per;
  int tmp = rest / per;            // 0..7
  int y = tmp & 3;                 // D tiles of 256
  int ks = tmp >> 2;               // split-K half
  int bx = (wid & 7) * per + bxi;
  if (bx >= mt) return;
  int row0 = chunk_base + bx * 128;
  int total = off[E_];
  if (row0 >= total) return;
  int e = 0;
  while (e < E_ - 1 && off[e + 1] <= row0) e++;
  int d0 = y * 256;
  int tid = threadIdx.x;
  int lane = tid & 63;
  int w8 = tid >> 6;
  int wm = w8 >> 2, wn = w8 & 3;
  int l15 = lane & 15, quad = (lane >> 4) & 3;

  int ksbase = ks * 2048;
  int arow = tid >> 2, asl = tid & 3;
  int csA = asl ^ ((arow >> 1) & 3);
  const ushort* apA = H + (size_t)(bx * 128 + arow) * F_ + ksbase + csA * 8;
  int br1 = 128 + arow;
  int csB0 = asl ^ ((arow >> 1) & 3);
  int csB1 = asl ^ ((br1 >> 1) & 3);
  const ushort* bp0 = W2bt + ((size_t)e * D_ + d0 + arow) * F_ + ksbase + csB0 * 8;
  const ushort* bp1 = W2bt + ((size_t)e * D_ + d0 + br1) * F_ + ksbase + csB1 * 8;
  int ldA  = (tid & 448) * 8;
  int ldB0 = 4096 + (tid & 448) * 8;
  int ldB1 = 8192 + (tid & 448) * 8;

  f32x4 acc[4][4];
  f32x4 zz = {0.f, 0.f, 0.f, 0.f};
#pragma unroll
  for (int i = 0; i < 4; i++)
#pragma unroll
    for (int j = 0; j < 4; j++) acc[i][j] = zz;

  G_PROLOGUE();
  G_LOOP(64);          // 2048 / 32 per K-half

  // epilogue: f32 atomic add (exactly 2 contributions per element onto zeroed Ya)
#pragma unroll
  for (int i = 0; i < 4; i++) {
    int mrow = wm * 64 + i * 16 + quad * 4;
#pragma unroll
    for (int rg = 0; rg < 4; rg++) {
      size_t base = (size_t)(row0 + mrow + rg) * D_ + d0;
#pragma unroll
      for (int j = 0; j < 4; j++) {
        int cc = wn * 64 + j * 16 + l15;
        atomicAdd(Ya + base + cc, acc[i][j][rg]);
      }
    }
  }
}

// ============ fallback GEMMs (validated round-2 code), used only if ws is small ============
template<bool XB, bool BT>
__global__ __launch_bounds__(256) void gemm1_kernel(
    const float* __restrict__ x, const ushort* __restrict__ xb,
    const ushort* __restrict__ W1bt, const float* __restrict__ W1nat,
    const float* __restrict__ b1, const int* __restrict__ rowtok,
    const int* __restrict__ off, ushort* __restrict__ H, int chunk_base)
{
  __shared__ ushort As[128 * 72];
  __shared__ ushort Bs[128 * 72];
  int row0 = chunk_base + blockIdx.x * 128;
  int total = off[E_];
  if (row0 >= total) return;
  int e = 0;
  while (e < E_ - 1 && off[e + 1] <= row0) e++;
  int f0 = blockIdx.y * 128;
  int tid = threadIdx.x;
  int wave = tid >> 6, lane = tid & 63;
  int wm = wave & 1, wn = wave >> 1;
  int l15 = lane & 15, quad = lane >> 4;

  int r = tid >> 1, h = tid & 1;
  int tokA = rowtok[row0 + r];
  size_t aoff = ((tokA >= 0) ? (size_t)tokA * D_ : 0) + h * 32;

  f32x4 acc[4][4];
  f32x4 zz = {0.f, 0.f, 0.f, 0.f};
  for (int i = 0; i < 4; i++) for (int j = 0; j < 4; j++) acc[i][j] = zz;

  for (int k0 = 0; k0 < D_; k0 += 64) {
    for (int q = 0; q < 4; q++) {
      uint4 v;
      if (tokA >= 0) {
        if (XB) {
          v = *(const uint4*)(xb + aoff + k0 + q * 8);
        } else {
          float4 fa = *(const float4*)(x + aoff + k0 + q * 8);
          float4 fb = *(const float4*)(x + aoff + k0 + q * 8 + 4);
          ushort t8[8] = {f2bf(fa.x), f2bf(fa.y), f2bf(fa.z), f2bf(fa.w),
                          f2bf(fb.x), f2bf(fb.y), f2bf(fb.z), f2bf(fb.w)};
          v = *(const uint4*)t8;
        }
      } else v = make_uint4(0u, 0u, 0u, 0u);
      *(uint4*)&As[r * 72 + h * 32 + q * 8] = v;
    }
    if (BT) {
      const ushort* bs = W1bt + ((size_t)e * F_ + f0 + r) * D_ + k0 + h * 32;
      for (int q = 0; q < 4; q++)
        *(uint4*)&Bs[r * 72 + h * 32 + q * 8] = *(const uint4*)(bs + q * 8);
    } else {
      for (int i = 0; i < 8; i++) {
        int c = tid + i * 256;
        int kk = c >> 5;
        int n4 = (c & 31) * 4;
        float4 v = *(const float4*)(W1nat + (size_t)e * D_ * F_ +
                                    (size_t)(k0 + kk) * F_ + f0 + n4);
        Bs[(n4 + 0) * 72 + kk] = f2bf(v.x);
        Bs[(n4 + 1) * 72 + kk] = f2bf(v.y);
        Bs[(n4 + 2) * 72 + kk] = f2bf(v.z);
        Bs[(n4 + 3) * 72 + kk] = f2bf(v.w);
      }
    }
    __syncthreads();
    for (int s = 0; s < 2; s++) {
      int kc = s * 32 + quad * 8;
      short8 a[4], b[4];
      for (int i = 0; i < 4; i++)
        a[i] = *(const short8*)&As[(wm * 64 + i * 16 + l15) * 72 + kc];
      for (int j = 0; j < 4; j++)
        b[j] = *(const short8*)&Bs[(wn * 64 + j * 16 + l15) * 72 + kc];
      for (int i = 0; i < 4; i++)
        for (int j = 0; j < 4; j++)
          acc[i][j] = mfma16(a[i], b[j], acc[i][j]);
    }
    __syncthreads();
  }

  float bv[4];
  for (int j = 0; j < 4; j++)
    bv[j] = b1[e * F_ + f0 + wn * 64 + j * 16 + l15];
  ushort* Hb = H + (size_t)(row0 - chunk_base) * F_;
  for (int i = 0; i < 4; i++) {
    int mrow = wm * 64 + i * 16 + quad * 4;
    for (int rg = 0; rg < 4; rg++) {
      ushort* dst = Hb + (size_t)(mrow + rg) * F_ + f0;
      for (int j = 0; j < 4; j++) {
        float vv = acc[i][j][rg] + bv[j];
        vv = vv > 0.f ? vv : 0.f;
        dst[wn * 64 + j * 16 + l15] = f2bf(vv);
      }
    }
  }
}

template<bool YF32>
__global__ __launch_bounds__(256) void gemm2_kernel(
    const ushort* __restrict__ H, const float* __restrict__ W2nat,
    const int* __restrict__ off, void* __restrict__ Ya, int chunk_base)
{
  __shared__ ushort As[128 * 72];
  __shared__ ushort Bs[128 * 72];
  int row0 = chunk_base + blockIdx.x * 128;
  int total = off[E_];
  if (row0 >= total) return;
  int e = 0;
  while (e < E_ - 1 && off[e + 1] <= row0) e++;
  int d0 = blockIdx.y * 128;
  int tid = threadIdx.x;
  int wave = tid >> 6, lane = tid & 63;
  int wm = wave & 1, wn = wave >> 1;
  int l15 = lane & 15, quad = lane >> 4;

  int r = tid >> 1, h = tid & 1;
  const ushort* aSrc = H + (size_t)(blockIdx.x * 128 + r) * F_ + h * 32;

  f32x4 acc[4][4];
  f32x4 zz = {0.f, 0.f, 0.f, 0.f};
  for (int i = 0; i < 4; i++) for (int j = 0; j < 4; j++) acc[i][j] = zz;

  for (int k0 = 0; k0 < F_; k0 += 64) {
    for (int q = 0; q < 4; q++)
      *(uint4*)&As[r * 72 + h * 32 + q * 8] = *(const uint4*)(aSrc + k0 + q * 8);
    for (int i = 0; i < 8; i++) {
      int c = tid + i * 256;
      int kk = c >> 5;
      int n4 = (c & 31) * 4;
      float4 v = *(const float4*)(W2nat + (size_t)e * F_ * D_ +
                                  (size_t)(k0 + kk) * D_ + d0 + n4);
      Bs[(n4 + 0) * 72 + kk] = f2bf(v.x);
      Bs[(n4 + 1) * 72 + kk] = f2bf(v.y);
      Bs[(n4 + 2) * 72 + kk] = f2bf(v.z);
      Bs[(n4 + 3) * 72 + kk] = f2bf(v.w);
    }
    __syncthreads();
    for (int s = 0; s < 2; s++) {
      int kc = s * 32 + quad * 8;
      short8 a[4], b[4];
      for (int i = 0; i < 4; i++)
        a[i] = *(const short8*)&As[(wm * 64 + i * 16 + l15) * 72 + kc];
      for (int j = 0; j < 4; j++)
        b[j] = *(const short8*)&Bs[(wn * 64 + j * 16 + l15) * 72 + kc];
      for (int i = 0; i < 4; i++)
        for (int j = 0; j < 4; j++)
          acc[i][j] = mfma16(a[i], b[j], acc[i][j]);
    }
    __syncthreads();
  }

  for (int i = 0; i < 4; i++) {
    int mrow = wm * 64 + i * 16 + quad * 4;
    for (int rg = 0; rg < 4; rg++) {
      size_t base = (size_t)(row0 + mrow + rg) * D_ + d0;
      for (int j = 0; j < 4; j++) {
        int cc = wn * 64 + j * 16 + l15;
        if (YF32) ((float*)Ya)[base + cc] = acc[i][j][rg];
        else ((ushort*)Ya)[base + cc] = f2bf(acc[i][j][rg]);
      }
    }
  }
}

// -------- combine: y[t] = w0*(Ya[p0]+b2[e0]) + w1*(Ya[p1]+b2[e1]) --------
template<bool YF32>
__global__ __launch_bounds__(256) void combine_kernel(
    const void* __restrict__ Ya, const float* __restrict__ b2,
    const int* __restrict__ tpos, const int* __restrict__ tke,
    const float* __restrict__ tkw, float* __restrict__ y)
{
  int t = blockIdx.x;
  int c = threadIdx.x * 4;
  int p0 = tpos[2 * t], p1 = tpos[2 * t + 1];
  int e0 = tke[2 * t], e1 = tke[2 * t + 1];
  float w0 = tkw[2 * t], w1 = tkw[2 * t + 1];
  float a0[4], a1[4];
  if (YF32) {
    float4 va = *(const float4*)((const float*)Ya + (size_t)p0 * D_ + c);
    float4 vb = *(const float4*)((const float*)Ya + (size_t)p1 * D_ + c);
    a0[0] = va.x; a0[1] = va.y; a0[2] = va.z; a0[3] = va.w;
    a1[0] = vb.x; a1[1] = vb.y; a1[2] = vb.z; a1[3] = vb.w;
  } else {
    uint2 ua = *(const uint2*)((const ushort*)Ya + (size_t)p0 * D_ + c);
    uint2 ub = *(const uint2*)((const ushort*)Ya + (size_t)p1 * D_ + c);
    const ushort* pa = (const ushort*)&ua;
    const ushort* pb = (const ushort*)&ub;
    for (int q = 0; q < 4; q++) {
      a0[q] = __uint_as_float(((uint32_t)pa[q]) << 16);
      a1[q] = __uint_as_float(((uint32_t)pb[q]) << 16);
    }
  }
  float4 vb0 = *(const float4*)(b2 + (size_t)e0 * D_ + c);
  float4 vb1 = *(const float4*)(b2 + (size_t)e1 * D_ + c);
  float4 o;
  o.x = w0 * (a0[0] + vb0.x) + w1 * (a1[0] + vb1.x);
  o.y = w0 * (a0[1] + vb0.y) + w1 * (a1[1] + vb1.y);
  o.z = w0 * (a0[2] + vb0.z) + w1 * (a1[2] + vb1.z);
  o.w = w0 * (a0[3] + vb0.w) + w1 * (a1[3] + vb1.w);
  *(float4*)(y + (size_t)t * D_ + c) = o;
}

extern "C" void kernel_launch(void* const* d_in, const int* in_sizes, int n_in,
                              void* d_out, int out_size, void* d_ws, size_t ws_size,
                              hipStream_t stream) {
  (void)in_sizes; (void)n_in; (void)out_size;
  const float* x  = (const float*)d_in[0];
  const float* Wr = (const float*)d_in[1];
  const float* W1 = (const float*)d_in[2];
  const float* b1 = (const float*)d_in[3];
  const float* W2 = (const float*)d_in[4];
  const float* b2 = (const float*)d_in[5];
  float* out = (float*)d_out;

  char* ws = (char*)d_ws;
  int*   cnt    = (int*)(ws + 0);
  int*   fill   = (int*)(ws + 32);
  float* imp    = (float*)(ws + 64);
  float* z2     = (float*)(ws + 96);
  int*   off    = (int*)(ws + 128);
  int*   tke    = (int*)(ws + 256);
  float* tkw    = (float*)(ws + 256 + 65536);
  int*   tpos   = (int*)(ws + 256 + 2 * 65536);
  int*   rowtok = (int*)(ws + 256 + 3 * 65536);
  size_t p = 256 + 3 * 65536 + (size_t)CAP * 4;
  p = (p + 4095) & ~(size_t)4095;

  const size_t XB_SZ = (size_t)NTOK * D_ * 2;          // 16.8 MB
  const size_t YA32  = (size_t)CAP * D_ * 4;           // 75.5 MB
  const size_t YA16  = (size_t)CAP * D_ * 2;           // 37.7 MB
  const size_t WT    = (size_t)E_ * D_ * F_ * 2;       // 67.1 MB
  const size_t HROW  = (size_t)F_ * 2;
  const size_t MINH  = 256 * HROW;                     // 2 MB

  bool xb_on = true, ya32 = true;
  if (ws_size < p + XB_SZ + YA32 + MINH) {
    ya32 = false;
    if (ws_size < p + XB_SZ + YA16 + MINH) xb_on = false;
  }
  ushort* xb = nullptr;
  if (xb_on) { xb = (ushort*)(ws + p); p += XB_SZ; }
  void* Ya = (void*)(ws + p);
  p += ya32 ? YA32 : YA16;

  bool w1t_on = false, w2t_on = false;
  ushort* W1bt = nullptr; ushort* W2bt = nullptr;
  if (ws_size >= p + WT + MINH) { w1t_on = true; W1bt = (ushort*)(ws + p); p += WT; }
  if (ws_size >= p + WT + MINH) { w2t_on = true; W2bt = (ushort*)(ws + p); p += WT; }

  size_t hav = ws_size > p ? ws_size - p : 0;
  long long chl = (long long)(hav / HROW);
  int CH = (int)(chl & ~255LL);
  if (CH < 256) CH = 256;
  if (CH > CAP) CH = CAP;    // R4-proven: full ws fits H entirely -> nchunks=1
  ushort* Hbuf = (ushort*)(ws + p);
  int nchunks = (CAP + CH - 1) / CH;

  bool g1fast = xb_on && w1t_on;
  bool g2fast = w2t_on && ya32;

  hipMemsetAsync(ws, 0, 128, stream);
  hipMemsetAsync(rowtok, 0xFF, (size_t)CAP * 4, stream);
  if (g2fast) hipMemsetAsync(Ya, 0, YA32, stream);   // split-K accumulates
  router_kernel<<<NTOK / 4, 256, 0, stream>>>(x, Wr, cnt, imp, z2, tke, tkw, xb);
  finalize_kernel<<<1, 64, 0, stream>>>(cnt, imp, z2, off, out + (size_t)NTOK * D_);
  scatter_kernel<<<NTOK / 256, 256, 0, stream>>>(tke, off, fill, rowtok, tpos);
  if (w1t_on)
    transpose_cast_kernel<<<dim3(F_ / 64, D_ / 64, E_), 256, 0, stream>>>(W1, W1bt, D_, F_);
  if (w2t_on)
    transpose_cast_kernel<<<dim3(D_ / 64, F_ / 64, E_), 256, 0, stream>>>(W2, W2bt, F_, D_);

  for (int c = 0; c < nchunks; c++) {
    int cb = c * CH;
    int mt = CH / 128;
    int perx = (mt + 7) >> 3;
    if (g1fast) {
      gemm1g_kernel<<<8 * perx * 16, 512, 0, stream>>>(xb, W1bt, b1, rowtok, off, Hbuf, cb, mt);
    } else {
      dim3 g1(CH / 128, F_ / 128);
      if (xb_on) gemm1_kernel<true, false><<<g1, 256, 0, stream>>>(x, xb, W1bt, W1, b1, rowtok, off, Hbuf, cb);
      else       gemm1_kernel<false, false><<<g1, 256, 0, stream>>>(x, xb, W1bt, W1, b1, rowtok, off, Hbuf, cb);
    }
    if (g2fast) {
      gemm2g_kernel<<<8 * perx * 8, 512, 0, stream>>>(Hbuf, W2bt, off, (float*)Ya, cb, mt);
    } else {
      dim3 g2(CH / 128, D_ / 128);
      if (ya32) gemm2_kernel<true><<<g2, 256, 0, stream>>>(Hbuf, W2, off, Ya, cb);
      else      gemm2_kernel<false><<<g2, 256, 0, stream>>>(Hbuf, W2, off, Ya, cb);
    }
  }
  if (ya32) combine_kernel<true><<<NTOK, 256, 0, stream>>>(Ya, b2, tpos, tke, tkw, out);
  else      combine_kernel<false><<<NTOK, 256, 0, stream>>>(Ya, b2, tpos, tke, tkw, out);
}